// Round 5
// baseline (782.713 us; speedup 1.0000x reference)
//
#include <hip/hip_runtime.h>
#include <math.h>

// x: (64,32,32,64) fp32 -> N=65536 rows, D=64; codebook K=1024.
// ws layout (floats): [0,1024) h_k = 0.5*||c_k||^2
//                     [1024, 1024+1024*1024) avg_prob partial slots [1024][1024]
//                     [WS_ACC,+4) accumulators: sqerr, ent_sum, avg_entropy
#define WS_H 0
#define WS_PART 1024
#define WS_ACC (1024 + 1024*1024)
#define LOSSOFF 4194304
#define IDXOFF  4194305

__global__ void vq_k0(const float* __restrict__ cb, float* __restrict__ ws) {
  int k = blockIdx.x * 256 + threadIdx.x;              // grid 4 -> k < 1024
  const float4* row = (const float4*)(cb + (k << 6));
  float s = 0.f;
  #pragma unroll
  for (int i = 0; i < 16; ++i) {
    float4 v = row[i];
    s += v.x * v.x + v.y * v.y + v.z * v.z + v.w * v.w;
  }
  ws[WS_H + k] = 0.5f * s;
  if (blockIdx.x == 0 && threadIdx.x < 4) ws[WS_ACC + threadIdx.x] = 0.f;
}

// Main kernel: 16 rows/block, grid 4096. Thread tile = 4 rows x 16 cols.
// Lane map: rl = lane&3 (row-lane), cg = lane>>2 (col-group). Rows = 4i+rl.
// Cols = j*64 + w*16 + cg  (j=0..15; chunk ch=j>>1 holds j=2ch,2ch+1).
// z' = 200*(x.c - 0.5*||c||^2): same softmax/argmin as -dist/T (row-const a^2 drops).
__launch_bounds__(256, 4)
__global__ void vq_k1(const float* __restrict__ x, const float* __restrict__ cb,
                      float* __restrict__ out, float* __restrict__ ws) {
  __shared__ float cbs[128 * 64];      // 32KB, XOR-swizzled: byte ^= (c&7)<<4
  __shared__ float xs[16][68];         // pad 68: 4-distinct-quad xv reads
  __shared__ float redM[4][16], redL[4][16], redS[4][16], redBV[4][16];
  __shared__ int   redBI[4][16];
  __shared__ float lseArr[16];
  __shared__ int   bestArr[16];
  __shared__ float entAcc;
  __shared__ float redQ[4];

  const int tid  = threadIdx.x;
  const int w    = tid >> 6;
  const int lane = tid & 63;
  const int rl   = lane & 3;
  const int cg   = lane >> 2;
  const int cbase = w * 16 + cg;       // 0..63: col offset within each 64-col j-stripe
  const int row0 = blockIdx.x << 4;

  {  // stage x tile (4KB) once
    const int xr = tid >> 4, xd = (tid & 15) << 2;
    *(float4*)&xs[xr][xd] = *(const float4*)(x + ((row0 + xr) << 6) + xd);
  }
  if (tid == 0) entAcc = 0.f;

  // init z with -h (h from global ws; L2-hot, once per block)
  float zb[4][16];
  #pragma unroll
  for (int j = 0; j < 16; ++j) {
    const float h = ws[WS_H + j * 64 + cbase];
    #pragma unroll
    for (int i = 0; i < 4; ++i) zb[i][j] = -h;
  }

  const int sw = (cbase & 7) << 4;     // (c&7)<<4; same for c and c+64
  const int b0 = cbase << 8;           // c0 = cbase       (local col of j=2ch)
  const int b1 = (cbase + 64) << 8;    // c1 = cbase + 64  (local col of j=2ch+1)

  #pragma unroll 1
  for (int ch = 0; ch < 8; ++ch) {
    __syncthreads();                   // previous chunk's readers done
    #pragma unroll
    for (int u = 0; u < 8; ++u) {      // stage 128x64 fp32 chunk, swizzled
      const int idx = (u << 8) + tid;  // float4 index 0..2047
      const int c = idx >> 4, dqq = idx & 15;
      const float4 v = *(const float4*)(cb + (((ch << 7) + c) << 6) + (dqq << 2));
      const int byteoff = (c << 8) + ((dqq << 4) ^ ((c & 7) << 4));
      *(float4*)((char*)cbs + byteoff) = v;
    }
    __syncthreads();                   // chunk ready (also orders xs on ch==0)

    #pragma unroll
    for (int dq = 0; dq < 16; ++dq) {
      const int dqo = (dq << 4) ^ sw;
      const float4 cv0 = *(const float4*)((const char*)cbs + b0 + dqo);
      const float4 cv1 = *(const float4*)((const char*)cbs + b1 + dqo);
      #pragma unroll
      for (int i = 0; i < 4; ++i) {
        const float4 xv = *(const float4*)&xs[(i << 2) + rl][dq << 2];
        float a0 = zb[i][2 * ch], a1 = zb[i][2 * ch + 1];
        a0 += xv.x * cv0.x; a0 += xv.y * cv0.y; a0 += xv.z * cv0.z; a0 += xv.w * cv0.w;
        a1 += xv.x * cv1.x; a1 += xv.y * cv1.y; a1 += xv.z * cv1.z; a1 += xv.w * cv1.w;
        zb[i][2 * ch] = a0; zb[i][2 * ch + 1] = a1;
      }
    }
  }

  #pragma unroll
  for (int i = 0; i < 4; ++i)
    #pragma unroll
    for (int j = 0; j < 16; ++j) zb[i][j] *= 200.f;   // z' scale (as round 2)

  // ---- pass 1: row max ----
  float m[4];
  #pragma unroll
  for (int i = 0; i < 4; ++i) {
    float mm = -INFINITY;
    #pragma unroll
    for (int j = 0; j < 16; ++j) mm = fmaxf(mm, zb[i][j]);
    m[i] = mm;
  }
  #pragma unroll
  for (int mk = 4; mk <= 32; mk <<= 1)
    #pragma unroll
    for (int i = 0; i < 4; ++i) m[i] = fmaxf(m[i], __shfl_xor(m[i], mk));
  if (cg == 0)
    #pragma unroll
    for (int i = 0; i < 4; ++i) redM[w][(i << 2) + rl] = m[i];
  __syncthreads();
  #pragma unroll
  for (int i = 0; i < 4; ++i) {
    const int row = (i << 2) + rl;
    m[i] = fmaxf(fmaxf(redM[0][row], redM[1][row]), fmaxf(redM[2][row], redM[3][row]));
  }

  // ---- pass 2: sumexp, sum(exp*z), argmax (first-index tie-break) ----
  float l[4] = {0.f, 0.f, 0.f, 0.f}, s[4] = {0.f, 0.f, 0.f, 0.f}, bv[4];
  int bi[4];
  #pragma unroll
  for (int i = 0; i < 4; ++i) { bv[i] = -INFINITY; bi[i] = 0x7FFFFFFF; }
  #pragma unroll
  for (int j = 0; j < 16; ++j) {
    const int col = j * 64 + cbase;
    #pragma unroll
    for (int i = 0; i < 4; ++i) {
      const float zi = zb[i][j];
      const float u = __expf(zi - m[i]);
      l[i] += u;
      s[i] += u * zi;
      if (zi > bv[i] || (zi == bv[i] && col < bi[i])) { bv[i] = zi; bi[i] = col; }
    }
  }
  #pragma unroll
  for (int mk = 4; mk <= 32; mk <<= 1) {
    #pragma unroll
    for (int i = 0; i < 4; ++i) {
      l[i] += __shfl_xor(l[i], mk);
      s[i] += __shfl_xor(s[i], mk);
      const float obv = __shfl_xor(bv[i], mk);
      const int   obi = __shfl_xor(bi[i], mk);
      if (obv > bv[i] || (obv == bv[i] && obi < bi[i])) { bv[i] = obv; bi[i] = obi; }
    }
  }
  if (cg == 0)
    #pragma unroll
    for (int i = 0; i < 4; ++i) {
      const int row = (i << 2) + rl;
      redL[w][row] = l[i]; redS[w][row] = s[i];
      redBV[w][row] = bv[i]; redBI[w][row] = bi[i];
    }
  __syncthreads();
  if (tid < 16) {                      // one finalizer per row
    float L = 0.f, S = 0.f, BV = -INFINITY;
    int BI = 0x7FFFFFFF;
    #pragma unroll
    for (int wv = 0; wv < 4; ++wv) {
      L += redL[wv][tid];
      S += redS[wv][tid];
      const float v = redBV[wv][tid];
      const int  ix = redBI[wv][tid];
      if (v > BV || (v == BV && ix < BI)) { BV = v; BI = ix; }
    }
    const float ZM = fmaxf(fmaxf(redM[0][tid], redM[1][tid]),
                           fmaxf(redM[2][tid], redM[3][tid]));
    const float lse = ZM + __logf(L);
    lseArr[tid] = lse;
    bestArr[tid] = BI;
    atomicAdd(&entAcc, lse - S / L);   // per-row sample entropy
    out[IDXOFF + row0 + tid] = (float)BI;
  }
  __syncthreads();

  // ---- pass 3: avg_prob accumulation (atomic into 1024 shared slots) ----
  float lseL[4];
  #pragma unroll
  for (int i = 0; i < 4; ++i) lseL[i] = lseArr[(i << 2) + rl];
  float* part = ws + WS_PART + (size_t)((blockIdx.x >> 2) << 10);
  #pragma unroll
  for (int j = 0; j < 16; ++j) {
    float ps = 0.f;
    #pragma unroll
    for (int i = 0; i < 4; ++i) ps += __expf(zb[i][j] - lseL[i]);
    ps += __shfl_xor(ps, 1);
    ps += __shfl_xor(ps, 2);           // sum over rl -> 16-row col sum
    if (rl == 0) atomicAdd(&part[j * 64 + cbase], ps);
  }

  // ---- epilogue: quantized output + squared-error ----
  float sqAcc = 0.f;
  {
    const int qr = tid >> 4, qd = (tid & 15) << 2;
    const int code = bestArr[qr];
    const float4 c4 = *(const float4*)(cb + (code << 6) + qd);
    const float4 x4 = *(const float4*)&xs[qr][qd];
    const float dx = c4.x - x4.x, dy = c4.y - x4.y, dz = c4.z - x4.z, dw = c4.w - x4.w;
    sqAcc = dx * dx + dy * dy + dz * dz + dw * dw;
    float4 o;                          // x + (q - x), as the reference STE
    o.x = x4.x + dx; o.y = x4.y + dy; o.z = x4.z + dz; o.w = x4.w + dw;
    *(float4*)(out + ((row0 + qr) << 6) + qd) = o;
  }
  #pragma unroll
  for (int mk = 1; mk <= 32; mk <<= 1) sqAcc += __shfl_xor(sqAcc, mk);
  if (lane == 0) redQ[w] = sqAcc;
  __syncthreads();
  if (tid == 0) {
    atomicAdd(ws + WS_ACC + 0, redQ[0] + redQ[1] + redQ[2] + redQ[3]);
    atomicAdd(ws + WS_ACC + 1, entAcc);
  }
}

// Reduce 1024 partial slots -> avg_probs -> avg_entropy contribution.
__global__ void vq_k2(float* __restrict__ ws) {
  __shared__ float sh[8][32];
  const int t = threadIdx.x;
  const int bl = t >> 5, cl = t & 31;
  const int k = blockIdx.x * 32 + cl;  // grid 32 -> k < 1024
  float s = 0.f;
  #pragma unroll 4
  for (int i = 0; i < 128; ++i)
    s += ws[WS_PART + ((bl << 7) + i) * 1024 + k];
  sh[bl][cl] = s;
  __syncthreads();
  if (t < 32) {
    float tot = 0.f;
    #pragma unroll
    for (int b = 0; b < 8; ++b) tot += sh[b][t];
    const float p = tot * (1.f / 65536.f);
    float c = -p * __logf(p + 1e-5f);
    c += __shfl_xor(c, 1);
    c += __shfl_xor(c, 2);
    c += __shfl_xor(c, 4);
    c += __shfl_xor(c, 8);
    c += __shfl_xor(c, 16);
    if (t == 0) atomicAdd(ws + WS_ACC + 2, c);
  }
}

__global__ void vq_k3(const float* __restrict__ ws, float* __restrict__ out) {
  if (threadIdx.x == 0) {
    const float msq  = ws[WS_ACC + 0] * (1.f / (65536.f * 64.f));
    const float sent = ws[WS_ACC + 1] * (1.f / 65536.f);
    const float aent = ws[WS_ACC + 2];
    out[LOSSOFF] = 1.25f * msq + 0.1f * (sent - aent);
  }
}

extern "C" void kernel_launch(void* const* d_in, const int* in_sizes, int n_in,
                              void* d_out, int out_size, void* d_ws, size_t ws_size,
                              hipStream_t stream) {
  (void)in_sizes; (void)n_in; (void)out_size; (void)ws_size;
  const float* x  = (const float*)d_in[0];
  const float* cb = (const float*)d_in[1];
  float* out = (float*)d_out;
  float* ws  = (float*)d_ws;

  vq_k0<<<dim3(4), dim3(256), 0, stream>>>(cb, ws);
  hipMemsetAsync(ws + WS_PART, 0, (size_t)1024 * 1024 * sizeof(float), stream);
  vq_k1<<<dim3(4096), dim3(256), 0, stream>>>(x, cb, out, ws);
  vq_k2<<<dim3(32), dim3(256), 0, stream>>>(ws);
  vq_k3<<<dim3(1), dim3(64), 0, stream>>>(ws, out);
}

// Round 8
// 298.096 us; speedup vs baseline: 2.6257x; 2.6257x over previous
//
#include <hip/hip_runtime.h>
#include <math.h>

// x: (64,32,32,64) fp32 -> N=65536 rows, D=64; codebook K=1024.
// ws layout (floats): [0,1024) hs_k = 100*||c_k||^2  (z = 200*dot - hs)
//                     [1024, 1024+1024*1024) avg_prob partial slots [1024][1024]
//                     [WS_ACC,+4) accumulators: sqerr, ent_sum, avg_entropy
#define WS_H 0
#define WS_PART 1024
#define WS_ACC (1024 + 1024*1024)
#define LOSSOFF 4194304
#define IDXOFF  4194305

__global__ void vq_k0(const float* __restrict__ cb, float* __restrict__ ws) {
  int k = blockIdx.x * 256 + threadIdx.x;              // grid 4 -> k < 1024
  const float4* row = (const float4*)(cb + (k << 6));
  float s = 0.f;
  #pragma unroll
  for (int i = 0; i < 16; ++i) {
    float4 v = row[i];
    s += v.x * v.x + v.y * v.y + v.z * v.z + v.w * v.w;
  }
  ws[WS_H + k] = 100.0f * s;                           // 200 * (0.5*||c||^2)
  if (blockIdx.x == 0 && threadIdx.x < 4) ws[WS_ACC + threadIdx.x] = 0.f;
}

// Main kernel: 32 rows/block, grid 2048. Thread tile = 4 rows x 4 cols per chunk.
// Lane map: cphase = lane&31 (32 col-phases), rphase = (w<<1)|(lane>>5) (8 row-phases).
// Thread rows = rphase*4 + i (i=0..3). Thread cols (chunk ch) = j*32 + cphase (j=0..3).
// zb[i][ch*4+j] holds dot(x_row, c_col); z = 200*dot - hs[col]. ALL indices static
// (ch/dq/u loops fully unrolled) -- rule #20: runtime-indexed arrays spill to scratch.
__launch_bounds__(256, 2)
__global__ void vq_k1(const float* __restrict__ x, const float* __restrict__ cb,
                      float* __restrict__ out, float* __restrict__ ws) {
  __shared__ float cbs[8192];          // 32KB chunk, XOR-swizzled: slot16 ^= (c&15)
  __shared__ float xs[32 * 64];        // 8KB, linear
  __shared__ float avgp[1024];         // 4KB per-block col prob sums
  __shared__ int   bestArr[32];
  __shared__ float entAcc;
  __shared__ float redQ[4];

  const int tid    = threadIdx.x;
  const int w      = tid >> 6;
  const int lane   = tid & 63;
  const int cphase = lane & 31;
  const int rphase = (w << 1) | (lane >> 5);   // 0..7
  const int row0   = blockIdx.x << 5;
  const int xbase  = rphase << 8;              // rphase*4 rows * 64 floats

  #pragma unroll
  for (int q = 0; q < 2; ++q) {                // stage x tile (8KB)
    const int idx = tid * 2 + q;
    const int r = idx >> 4, c16 = idx & 15;
    *(float4*)&xs[r * 64 + c16 * 4] = *(const float4*)(x + (size_t)(row0 + r) * 64 + c16 * 4);
  }
  ((float4*)avgp)[tid] = make_float4(0.f, 0.f, 0.f, 0.f);
  if (tid == 0) entAcc = 0.f;

  float zb[4][32];
  #pragma unroll
  for (int i = 0; i < 4; ++i)
    #pragma unroll
    for (int cc = 0; cc < 32; ++cc) zb[i][cc] = 0.f;

  const char* cbsb = (const char*)cbs;
  const int swl = (cphase & 15) << 4;          // swizzle bits for this thread's cols
  const int cb0 = cphase << 8;

  #pragma unroll
  for (int ch = 0; ch < 8; ++ch) {
    __syncthreads();                           // previous chunk's readers done (covers init on ch==0)
    #pragma unroll
    for (int u = 0; u < 8; ++u) {              // stage 128x64 chunk, swizzled
      const int idx = (u << 8) + tid;          // float4 index 0..2047
      const int c = idx >> 4, s16 = idx & 15;
      const float4 v = *(const float4*)(cb + (size_t)((ch << 7) + c) * 64 + s16 * 4);
      *(float4*)((char*)cbs + (c << 8) + (((s16 ^ (c & 15))) << 4)) = v;
    }
    __syncthreads();                           // chunk ready

    #pragma unroll
    for (int dq = 0; dq < 16; ++dq) {
      const int so = (dq << 4) ^ swl;
      const float4 cv0 = *(const float4*)(cbsb + cb0 +         so);
      const float4 cv1 = *(const float4*)(cbsb + cb0 +  8192 + so);   // +32 cols
      const float4 cv2 = *(const float4*)(cbsb + cb0 + 16384 + so);   // +64
      const float4 cv3 = *(const float4*)(cbsb + cb0 + 24576 + so);   // +96
      #pragma unroll
      for (int i = 0; i < 4; ++i) {
        const float4 xv = *(const float4*)&xs[xbase + i * 64 + dq * 4];
        float a0 = zb[i][ch * 4 + 0], a1 = zb[i][ch * 4 + 1];
        float a2 = zb[i][ch * 4 + 2], a3 = zb[i][ch * 4 + 3];
        a0 += xv.x * cv0.x; a0 += xv.y * cv0.y; a0 += xv.z * cv0.z; a0 += xv.w * cv0.w;
        a1 += xv.x * cv1.x; a1 += xv.y * cv1.y; a1 += xv.z * cv1.z; a1 += xv.w * cv1.w;
        a2 += xv.x * cv2.x; a2 += xv.y * cv2.y; a2 += xv.z * cv2.z; a2 += xv.w * cv2.w;
        a3 += xv.x * cv3.x; a3 += xv.y * cv3.y; a3 += xv.z * cv3.z; a3 += xv.w * cv3.w;
        zb[i][ch * 4 + 0] = a0; zb[i][ch * 4 + 1] = a1;
        zb[i][ch * 4 + 2] = a2; zb[i][ch * 4 + 3] = a3;
      }
    }
  }

  // ---- scale: z = 200*dot - hs[col] ----
  #pragma unroll
  for (int cc = 0; cc < 32; ++cc) {
    const int col = (cc >> 2) * 128 + (cc & 3) * 32 + cphase;
    const float hv = ws[WS_H + col];
    #pragma unroll
    for (int i = 0; i < 4; ++i) zb[i][cc] = fmaf(200.f, zb[i][cc], -hv);
  }

  // ---- pass 1: row max (thread-local, then butterfly over the 32 cphase lanes) ----
  float mx[4];
  #pragma unroll
  for (int i = 0; i < 4; ++i) {
    float mm = zb[i][0];
    #pragma unroll
    for (int cc = 1; cc < 32; ++cc) mm = fmaxf(mm, zb[i][cc]);
    mx[i] = mm;
  }
  #pragma unroll
  for (int mk = 1; mk <= 16; mk <<= 1)
    #pragma unroll
    for (int i = 0; i < 4; ++i) mx[i] = fmaxf(mx[i], __shfl_xor(mx[i], mk));

  // ---- pass 2: sumexp, sum(exp*z), argmax (first-index tie-break) ----
  float lsum[4] = {0.f, 0.f, 0.f, 0.f}, ssum[4] = {0.f, 0.f, 0.f, 0.f}, bval[4];
  int bidx[4];
  #pragma unroll
  for (int i = 0; i < 4; ++i) { bval[i] = -INFINITY; bidx[i] = 0x7FFFFFFF; }
  #pragma unroll
  for (int cc = 0; cc < 32; ++cc) {            // within-thread cols ascend with cc
    const int col = (cc >> 2) * 128 + (cc & 3) * 32 + cphase;
    #pragma unroll
    for (int i = 0; i < 4; ++i) {
      const float z = zb[i][cc];
      const float u = __expf(z - mx[i]);
      lsum[i] += u;
      ssum[i] += u * z;
      if (z > bval[i]) { bval[i] = z; bidx[i] = col; }  // strict > keeps first (lowest col)
    }
  }
  #pragma unroll
  for (int mk = 1; mk <= 16; mk <<= 1) {
    #pragma unroll
    for (int i = 0; i < 4; ++i) {
      lsum[i] += __shfl_xor(lsum[i], mk);
      ssum[i] += __shfl_xor(ssum[i], mk);
      const float ov = __shfl_xor(bval[i], mk);
      const int   oi = __shfl_xor(bidx[i], mk);
      if (ov > bval[i] || (ov == bval[i] && oi < bidx[i])) { bval[i] = ov; bidx[i] = oi; }
    }
  }
  float lse[4];
  #pragma unroll
  for (int i = 0; i < 4; ++i) lse[i] = mx[i] + __logf(lsum[i]);

  if (cphase == 0) {                            // one writer per half-wave (per 4 rows)
    float e = 0.f;
    #pragma unroll
    for (int i = 0; i < 4; ++i) {
      const int row = rphase * 4 + i;
      bestArr[row] = bidx[i];
      out[IDXOFF + row0 + row] = (float)bidx[i];
      e += lse[i] - ssum[i] / lsum[i];          // per-row sample entropy
    }
    atomicAdd(&entAcc, e);
  }

  // ---- pass 3: per-col prob sums into LDS (merge 2 half-waves, then 4-way ds atomics) ----
  #pragma unroll
  for (int cc = 0; cc < 32; ++cc) {
    const int col = (cc >> 2) * 128 + (cc & 3) * 32 + cphase;
    float p = 0.f;
    #pragma unroll
    for (int i = 0; i < 4; ++i) p += __expf(zb[i][cc] - lse[i]);
    p += __shfl_xor(p, 32);                     // same cphase, other rphase half
    if (lane < 32) atomicAdd(&avgp[col], p);
  }
  __syncthreads();                              // avgp + bestArr ready

  // ---- flush avg_prob partials (2 blocks share a slot) ----
  {
    float* slot = ws + WS_PART + (size_t)(blockIdx.x >> 1) * 1024;
    #pragma unroll
    for (int q = 0; q < 4; ++q) atomicAdd(&slot[q * 256 + tid], avgp[q * 256 + tid]);
  }

  // ---- epilogue: quantized output + squared-error ----
  float sq = 0.f;
  #pragma unroll
  for (int q = 0; q < 2; ++q) {
    const int idx = tid * 2 + q;
    const int r = idx >> 4, c16 = idx & 15;
    const int code = bestArr[r];
    const float4 c4 = *(const float4*)(cb + (size_t)code * 64 + c16 * 4);
    const float4 x4 = *(const float4*)&xs[r * 64 + c16 * 4];
    const float dx = c4.x - x4.x, dy = c4.y - x4.y, dz = c4.z - x4.z, dw = c4.w - x4.w;
    sq += dx * dx + dy * dy + dz * dz + dw * dw;
    float4 o;                                   // x + (q - x), as the reference STE
    o.x = x4.x + dx; o.y = x4.y + dy; o.z = x4.z + dz; o.w = x4.w + dw;
    *(float4*)(out + (size_t)(row0 + r) * 64 + c16 * 4) = o;
  }
  #pragma unroll
  for (int mk = 1; mk <= 32; mk <<= 1) sq += __shfl_xor(sq, mk);
  if (lane == 0) redQ[w] = sq;
  __syncthreads();
  if (tid == 0) {
    atomicAdd(ws + WS_ACC + 0, redQ[0] + redQ[1] + redQ[2] + redQ[3]);
    atomicAdd(ws + WS_ACC + 1, entAcc);
  }
}

// Reduce 1024 partial slots -> avg_probs -> avg_entropy contribution.
__global__ void vq_k2(float* __restrict__ ws) {
  __shared__ float sh[8][32];
  const int t = threadIdx.x;
  const int bl = t >> 5, cl = t & 31;
  const int k = blockIdx.x * 32 + cl;  // grid 32 -> k < 1024
  float s = 0.f;
  #pragma unroll 4
  for (int i = 0; i < 128; ++i)
    s += ws[WS_PART + ((bl << 7) + i) * 1024 + k];
  sh[bl][cl] = s;
  __syncthreads();
  if (t < 32) {
    float tot = 0.f;
    #pragma unroll
    for (int b = 0; b < 8; ++b) tot += sh[b][t];
    const float p = tot * (1.f / 65536.f);
    float c = -p * __logf(p + 1e-5f);
    c += __shfl_xor(c, 1);
    c += __shfl_xor(c, 2);
    c += __shfl_xor(c, 4);
    c += __shfl_xor(c, 8);
    c += __shfl_xor(c, 16);
    if (t == 0) atomicAdd(ws + WS_ACC + 2, c);
  }
}

__global__ void vq_k3(const float* __restrict__ ws, float* __restrict__ out) {
  if (threadIdx.x == 0) {
    const float msq  = ws[WS_ACC + 0] * (1.f / (65536.f * 64.f));
    const float sent = ws[WS_ACC + 1] * (1.f / 65536.f);
    const float aent = ws[WS_ACC + 2];
    out[LOSSOFF] = 1.25f * msq + 0.1f * (sent - aent);
  }
}

extern "C" void kernel_launch(void* const* d_in, const int* in_sizes, int n_in,
                              void* d_out, int out_size, void* d_ws, size_t ws_size,
                              hipStream_t stream) {
  (void)in_sizes; (void)n_in; (void)out_size; (void)ws_size;
  const float* x  = (const float*)d_in[0];
  const float* cb = (const float*)d_in[1];
  float* out = (float*)d_out;
  float* ws  = (float*)d_ws;

  vq_k0<<<dim3(4), dim3(256), 0, stream>>>(cb, ws);
  hipMemsetAsync(ws + WS_PART, 0, (size_t)1024 * 1024 * sizeof(float), stream);
  vq_k1<<<dim3(2048), dim3(256), 0, stream>>>(x, cb, out, ws);
  vq_k2<<<dim3(32), dim3(256), 0, stream>>>(ws);
  vq_k3<<<dim3(1), dim3(64), 0, stream>>>(ws, out);
}